// Round 9
// baseline (4817.250 us; speedup 1.0000x reference)
//
#include <hip/hip_runtime.h>

#define B_   256
#define T_   512
#define DIN_ 128
#define H_   512
#define G4_  2048

typedef __bf16 bf16_t;
typedef __bf16 bf16x8 __attribute__((ext_vector_type(8)));
typedef __bf16 bf16x4 __attribute__((ext_vector_type(4)));
typedef float  f32x4  __attribute__((ext_vector_type(4)));
typedef float  f32x16 __attribute__((ext_vector_type(16)));

// coherent-point read (sc0|sc1 = 1|16): bypass L1+L2, read the MALL
__device__ __forceinline__ void gload16cc(const void* g, void* l) {
  __builtin_amdgcn_global_load_lds(
      (const __attribute__((address_space(1))) unsigned int*)g,
      (__attribute__((address_space(3))) unsigned int*)l, 16, 0, 17);
}

__device__ __forceinline__ int fload(const int* p) {
  return __hip_atomic_load(p, __ATOMIC_RELAXED, __HIP_MEMORY_SCOPE_AGENT);
}

// ---------------- prep ----------------
__global__ void cast_f32_bf16(const float* __restrict__ s, bf16_t* __restrict__ d, int n) {
  int i = (blockIdx.x * 256 + threadIdx.x) * 4;
  if (i >= n) return;
  float4 v = *(const float4*)(s + i);
  bf16x4 o;
  o[0] = (bf16_t)v.x; o[1] = (bf16_t)v.y; o[2] = (bf16_t)v.z; o[3] = (bf16_t)v.w;
  *(bf16x4*)(d + i) = o;
}

// src f32 [2048][Ks] -> dst bf16 rows stride Kd at col offset coff
__global__ void cast_strided(const float* __restrict__ s, bf16_t* __restrict__ d,
                             int Ks, int Kd, int coff) {
  int npr = Ks >> 3;
  int i = blockIdx.x * 256 + threadIdx.x;
  if (i >= 2048 * npr) return;
  int row = i / npr, j = i - row * npr;
  const float* sp = s + (size_t)row * Ks + j * 8;
  float4 v0 = *(const float4*)sp;
  float4 v1 = *(const float4*)(sp + 4);
  bf16x8 o;
  o[0] = (bf16_t)v0.x; o[1] = (bf16_t)v0.y; o[2] = (bf16_t)v0.z; o[3] = (bf16_t)v0.w;
  o[4] = (bf16_t)v1.x; o[5] = (bf16_t)v1.y; o[6] = (bf16_t)v1.z; o[7] = (bf16_t)v1.w;
  *(bf16x8*)(d + (size_t)row * Kd + coff + j * 8) = o;
}

__global__ void bias_sum(const float* __restrict__ a, const float* __restrict__ b,
                         float* __restrict__ o, int n) {
  int i = blockIdx.x * 256 + threadIdx.x;
  if (i < n) o[i] = a[i] + b[i];
}

// ---------------- persistent 3-layer LSTM ----------------
// 192 blocks = 3 layers x 4 batch-groups(64 rows) x 16 u-slices(32 units).
// 8 waves = 4 gates x 2 K-halves, MFMA 32x32x16, W register-resident.
// Round-7 barrier structure (__syncthreads only) + (1) stage-H issued
// mid-X-phase, (2) early non-blocking flag loads, (3) conditional tail
// prefetch of X(s+1) gated by a sampled prev-flag (LDS-broadcast).
#define RING_N (8 * 256 * 512)
#define FSTR   16        // ints per flag (64B line)
#define BC_OFF 131072    // LDS byte offset of the 2-int broadcast

template<bool L0>
__device__ __forceinline__ void step_loop(
    char* smem, const bf16_t* __restrict__ xbf, const bf16_t* __restrict__ wcl,
    const float* __restrict__ bias_l, bf16_t* ringPrev, bf16_t* ringOwn,
    float* __restrict__ hsf, int* flags, int layer, int bg, int ug)
{
  constexpr int KL   = L0 ? 640 : 1024;
  constexpr int ROWB = KL * 2;          // LDS row bytes (X | H regions)
  constexpr int XT   = L0 ? 4 : 16;     // X-phase k-tiles(16) per wave
  constexpr int HT   = 16;              // H-phase k-tiles per wave
  constexpr int XP1  = L0 ? 2 : 8;      // X-MFMA tiles before stage-H issue
  constexpr int HOFF = L0 ? 256 : 1024; // byte offset of H region in a row
  const int tid  = threadIdx.x;
  const int lane = tid & 63;
  const int wv   = tid >> 6;
  const int g    = wv & 3;              // gate 0..3 (i,f,g,o)
  const int kh   = wv >> 2;             // K-half 0/1
  const int r32  = lane & 31;
  const int l5   = lane >> 5;
  const int u0   = ug * 32;
  const int t0x  = L0 ? (kh * 4) : (kh * 16);
  const int t0h  = L0 ? (8 + kh * 16) : (32 + kh * 16);

  // W fragments: lane holds W[g*512+u0+r32][tile*16 + l5*8 ..+8]
  bf16x8 wfrag[XT + HT];
  {
    const bf16_t* wrow = wcl + (size_t)(g * 512 + u0 + r32) * KL + l5 * 8;
    #pragma unroll
    for (int i = 0; i < XT; ++i) wfrag[i]      = *(const bf16x8*)(wrow + (t0x + i) * 16);
    #pragma unroll
    for (int i = 0; i < HT; ++i) wfrag[XT + i] = *(const bf16x8*)(wrow + (t0h + i) * 16);
  }
  const int um = tid >> 3;
  const int uq = tid & 7;
  float bsv[4][4];
  #pragma unroll
  for (int g2 = 0; g2 < 4; ++g2)
    #pragma unroll
    for (int q = 0; q < 4; ++q)
      bsv[g2][q] = bias_l[g2 * 512 + u0 + uq * 4 + q];

  float cst[4] = {0.f, 0.f, 0.f, 0.f};

  int* fl_own  = flags + ((layer * 512) * 4 + bg) * FSTR;
  int* fl_prev = flags + (((layer - 1) * 512) * 4 + bg) * FSTR;
  int* fl_next = flags + (((layer + 1) * 512) * 4 + bg) * FSTR;
  int* bc      = (int*)(smem + BC_OFF);   // [2] double-buffered "X staged" flag

  if (tid == 0) { bc[0] = 0; bc[1] = 0; }
  __syncthreads();

  bf16x8 xv0 = {}, xv1 = {};   // L0: x(s+1) prefetch regs

  for (int s = 0; s < 512; ++s) {
    const int slot  = s & 7;
    const int slot2 = (s - 1) & 7;
    // ---- slow path: X(s) was not tail-staged last step (startup/fallback)
    if (!bc[s & 1]) {
      if (!L0) {
        if (tid == 0)
          while (fload(fl_prev + s * 4 * FSTR) < 16) __builtin_amdgcn_s_sleep(1);
        __syncthreads();
        const bf16_t* prvS = ringPrev + (size_t)slot * (256 * 512) + (size_t)(bg * 64) * 512;
        #pragma unroll
        for (int i = 0; i < 8; ++i) {
          int r = i * 8 + wv;
          gload16cc(prvS + r * 512 + (lane ^ (r & 15)) * 8, smem + r * ROWB);
        }
      } else {
        int r0 = tid >> 4, c0 = tid & 15;
        bf16x8 v0 = *(const bf16x8*)(xbf + ((size_t)(bg * 64 + r0) * T_ + s) * 128 + c0 * 8);
        int i1 = 512 + tid, r1 = i1 >> 4, c1 = i1 & 15;
        bf16x8 v1 = *(const bf16x8*)(xbf + ((size_t)(bg * 64 + r1) * T_ + s) * 128 + c1 * 8);
        *(bf16x8*)(smem + r0 * ROWB + (c0 ^ (r0 & 15)) * 16) = v0;
        *(bf16x8*)(smem + r1 * ROWB + (c1 ^ (r1 & 15)) * 16) = v1;
      }
      __syncthreads();   // X(s) staged + visible
    }
    // ---- early flag loads (RT hides under X-MFMA part1); never block here
    int v_own = 16, v_next = 16, v_pn = 0;
    if (tid == 0) {
      if (s > 0)               v_own  = fload(fl_own  + (s - 1) * 4 * FSTR);
      if (layer < 2 && s >= 8) v_next = fload(fl_next + (s - 8) * 4 * FSTR);
      if (!L0 && s + 1 < 512)  v_pn   = fload(fl_prev + (s + 1) * 4 * FSTR);
    }
    f32x16 acc0 = {}, acc1 = {};
    // ---- X-MFMA part 1
    #pragma unroll
    for (int i = 0; i < XP1; ++i) {
      const int px = ((t0x + i) * 2 + l5) ^ (r32 & 15);
      bf16x8 a0 = *(const bf16x8*)(smem + (size_t)r32 * ROWB + px * 16);
      bf16x8 a1 = *(const bf16x8*)(smem + (size_t)(32 + r32) * ROWB + px * 16);
      acc0 = __builtin_amdgcn_mfma_f32_32x32x16_bf16(a0, wfrag[i], acc0, 0, 0, 0);
      acc1 = __builtin_amdgcn_mfma_f32_32x32x16_bf16(a1, wfrag[i], acc1, 0, 0, 0);
    }
    // ---- finish polls; publish "X(s+1) will be tail-staged" decision
    if (tid == 0) {
      while (v_own < 16)  { __builtin_amdgcn_s_sleep(1); v_own  = fload(fl_own  + (s - 1) * 4 * FSTR); }
      while (v_next < 16) { __builtin_amdgcn_s_sleep(1); v_next = fload(fl_next + (s - 8) * 4 * FSTR); }
      bc[(s + 1) & 1] = (s + 1 < 512) && (L0 || v_pn >= 16);
    }
    __syncthreads();                // (c) own flag seen by all
    // ---- stage-H(s) issue; RT covered by X-MFMA part 2
    {
      const bf16_t* ownS = ringOwn + (size_t)slot2 * (256 * 512) + (size_t)(bg * 64) * 512;
      #pragma unroll
      for (int i = 0; i < 8; ++i) {
        int r = i * 8 + wv;
        gload16cc(ownS + r * 512 + (lane ^ (r & 15)) * 8, smem + r * ROWB + HOFF);
      }
    }
    #pragma unroll
    for (int i = XP1; i < XT; ++i) {
      const int px = ((t0x + i) * 2 + l5) ^ (r32 & 15);
      bf16x8 a0 = *(const bf16x8*)(smem + (size_t)r32 * ROWB + px * 16);
      bf16x8 a1 = *(const bf16x8*)(smem + (size_t)(32 + r32) * ROWB + px * 16);
      acc0 = __builtin_amdgcn_mfma_f32_32x32x16_bf16(a0, wfrag[i], acc0, 0, 0, 0);
      acc1 = __builtin_amdgcn_mfma_f32_32x32x16_bf16(a1, wfrag[i], acc1, 0, 0, 0);
    }
    __syncthreads();                // (d) H staged + visible
    if (L0 && s + 1 < 512) {        // x(s+1) -> regs, RT hides under H-MFMA
      int r0 = tid >> 4, c0 = tid & 15;
      xv0 = *(const bf16x8*)(xbf + ((size_t)(bg * 64 + r0) * T_ + (s + 1)) * 128 + c0 * 8);
      int i1 = 512 + tid, r1 = i1 >> 4, c1 = i1 & 15;
      xv1 = *(const bf16x8*)(xbf + ((size_t)(bg * 64 + r1) * T_ + (s + 1)) * 128 + c1 * 8);
    }
    // ---- H-MFMA
    #pragma unroll
    for (int i = 0; i < HT; ++i) {
      const int px = ((t0h + i) * 2 + l5) ^ (r32 & 15);
      bf16x8 a0 = *(const bf16x8*)(smem + (size_t)r32 * ROWB + px * 16);
      bf16x8 a1 = *(const bf16x8*)(smem + (size_t)(32 + r32) * ROWB + px * 16);
      acc0 = __builtin_amdgcn_mfma_f32_32x32x16_bf16(a0, wfrag[XT + i], acc0, 0, 0, 0);
      acc1 = __builtin_amdgcn_mfma_f32_32x32x16_bf16(a1, wfrag[XT + i], acc1, 0, 0, 0);
    }
    __syncthreads();                // (e) all A-reads done: H overlay writable
    // ---- partials into H-region overlay [row][HOFF + kh*512 + n*4]
    {
      char* pb = smem + HOFF + kh * 512 + (g * 32 + r32) * 4;
      #pragma unroll
      for (int reg = 0; reg < 16; ++reg) {
        int mr = (reg & 3) + 8 * (reg >> 2) + 4 * l5;
        *(float*)(pb + (size_t)mr * ROWB)        = acc0[reg];
        *(float*)(pb + (size_t)(32 + mr) * ROWB) = acc1[reg];
      }
    }
    __syncthreads();                // (f) partials visible
    // ---- conditional tail stage-X(s+1): RT hides under update+publish
    if (bc[(s + 1) & 1]) {
      if (!L0) {
        const bf16_t* prvS = ringPrev + (size_t)((s + 1) & 7) * (256 * 512) + (size_t)(bg * 64) * 512;
        #pragma unroll
        for (int i = 0; i < 8; ++i) {
          int r = i * 8 + wv;
          gload16cc(prvS + r * 512 + (lane ^ (r & 15)) * 8, smem + r * ROWB);
        }
      } else {
        int r0 = tid >> 4, c0 = tid & 15;
        *(bf16x8*)(smem + r0 * ROWB + (c0 ^ (r0 & 15)) * 16) = xv0;
        int i1 = 512 + tid, r1 = i1 >> 4, c1 = i1 & 15;
        *(bf16x8*)(smem + r1 * ROWB + (c1 ^ (r1 & 15)) * 16) = xv1;
      }
    }
    // ---- lane-local c/h update (sum 2 K-half partials)
    union { bf16x4 v; unsigned long long u; } pk;
    f32x4 hvf;
    {
      const char* gpb = smem + (size_t)um * ROWB + HOFF;
      f32x4 gv[4];
      #pragma unroll
      for (int g2 = 0; g2 < 4; ++g2) {
        f32x4 p0 = *(const f32x4*)(gpb + (g2 * 32 + uq * 4) * 4);
        f32x4 p1 = *(const f32x4*)(gpb + 512 + (g2 * 32 + uq * 4) * 4);
        #pragma unroll
        for (int q = 0; q < 4; ++q) gv[g2][q] = p0[q] + p1[q];
      }
      #pragma unroll
      for (int q = 0; q < 4; ++q) {
        float i_ = gv[0][q] + bsv[0][q];
        float f_ = gv[1][q] + bsv[1][q];
        float g_ = gv[2][q] + bsv[2][q];
        float o_ = gv[3][q] + bsv[3][q];
        float si = 1.f / (1.f + __expf(-i_));
        float sf = 1.f / (1.f + __expf(-f_));
        float so = 1.f / (1.f + __expf(-o_));
        float tg = 2.f / (1.f + __expf(-2.f * g_)) - 1.f;
        float cv = sf * cst[q] + si * tg;
        cst[q] = cv;
        float th = 2.f / (1.f + __expf(-2.f * cv)) - 1.f;
        hvf[q] = so * th;
        pk.v[q] = (bf16_t)hvf[q];
      }
    }
    // ---- publish h(s) at the MALL (atomic RMW executes/allocates at MALL)
    {
      int b = bg * 64 + um;
      bf16_t* dst = ringOwn + (size_t)slot * (256 * 512) + (size_t)b * 512 + u0 + uq * 4;
      (void)__hip_atomic_exchange((unsigned long long*)dst, pk.u,
                                  __ATOMIC_RELAXED, __HIP_MEMORY_SCOPE_AGENT);
      if (layer == 2 && s == 511)
        *(f32x4*)(hsf + (size_t)b * 512 + u0 + uq * 4) = hvf;
    }
    __syncthreads();                // (g) drains publish + tail-stage DMAs
    if (tid == 0)
      atomicAdd(fl_own + s * 4 * FSTR, 1);   // fire-and-forget
  }
}

__global__ __launch_bounds__(512, 2)
void lstm_persist(const bf16_t* __restrict__ xbf, const bf16_t* __restrict__ wc,
                  const float* __restrict__ bias, bf16_t* __restrict__ rings,
                  float* __restrict__ hsf, int* __restrict__ flags)
{
  __shared__ __align__(16) char smem[131072 + 16];
  const int bid   = blockIdx.x;
  const int layer = bid >> 6;
  const int bg    = (bid >> 4) & 3;
  const int ug    = bid & 15;
  bf16_t* ringOwn  = rings + (size_t)layer * RING_N;
  bf16_t* ringPrev = rings + (size_t)(layer - 1) * RING_N;  // unused for layer0
  if (layer == 0) {
    step_loop<true>(smem, xbf, wc, bias, ringPrev, ringOwn, hsf, flags, 0, bg, ug);
  } else {
    const bf16_t* wcl = wc + 2048 * 640 + (size_t)(layer - 1) * 2048 * 1024;
    step_loop<false>(smem, xbf, wcl, bias + layer * 2048, ringPrev, ringOwn, hsf,
                     flags, layer, bg, ug);
  }
}

// ---------------- final FC ----------------
__global__ void fc_kernel(const float* __restrict__ h, const float* __restrict__ Wfc,
                          const float* __restrict__ bfc, float* __restrict__ out) {
  int b = blockIdx.x;
  int l = threadIdx.x;
  const float* hp = h + (size_t)b * H_;
  float acc = 0.f;
  #pragma unroll
  for (int i = 0; i < 8; ++i) acc += hp[l + i * 64] * Wfc[l + i * 64];
  #pragma unroll
  for (int off = 32; off; off >>= 1) acc += __shfl_down(acc, off, 64);
  if (l == 0) out[b] = acc + bfc[0];
}

// ---------------- host ----------------
extern "C" void kernel_launch(void* const* d_in, const int* in_sizes, int n_in,
                              void* d_out, int out_size, void* d_ws, size_t ws_size,
                              hipStream_t stream) {
  const float* x        = (const float*)d_in[0];
  const float* Wih_f[3] = {(const float*)d_in[1], (const float*)d_in[5], (const float*)d_in[9]};
  const float* Whh_f[3] = {(const float*)d_in[2], (const float*)d_in[6], (const float*)d_in[10]};
  const float* bih_f[3] = {(const float*)d_in[3], (const float*)d_in[7], (const float*)d_in[11]};
  const float* bhh_f[3] = {(const float*)d_in[4], (const float*)d_in[8], (const float*)d_in[12]};
  const float* Wfc = (const float*)d_in[13];
  const float* bfc = (const float*)d_in[14];

  char* ws = (char*)d_ws;
  size_t off = 0;
  auto take = [&](size_t bytes) { char* p = ws + off; off = (off + bytes + 255) & ~255ULL; return p; };
  bf16_t* XBF   = (bf16_t*)take((size_t)B_ * T_ * DIN_ * 2);        // 33.6 MB
  bf16_t* WC    = (bf16_t*)take((size_t)(2048*640 + 2*2048*1024) * 2); // 11.0 MB
  float*  BIAS  = (float*) take(3 * 2048 * 4);
  bf16_t* RINGS = (bf16_t*)take((size_t)3 * RING_N * 2);            // 6.3 MB
  float*  HSF   = (float*) take((size_t)B_ * H_ * 4);
  int*    FLAGS = (int*)   take(3 * 512 * 4 * FSTR * 4);            // 64B/flag

  bf16_t* WC1 = WC + 2048 * 640;
  bf16_t* WC2 = WC1 + 2048 * 1024;

  // weights / x prep
  cast_f32_bf16<<<16384, 256, 0, stream>>>(x, XBF, B_ * T_ * DIN_);
  cast_strided<<<128, 256, 0, stream>>>(Wih_f[0], WC,  128, 640, 0);
  cast_strided<<<512, 256, 0, stream>>>(Whh_f[0], WC,  512, 640, 128);
  cast_strided<<<512, 256, 0, stream>>>(Wih_f[1], WC1, 512, 1024, 0);
  cast_strided<<<512, 256, 0, stream>>>(Whh_f[1], WC1, 512, 1024, 512);
  cast_strided<<<512, 256, 0, stream>>>(Wih_f[2], WC2, 512, 1024, 0);
  cast_strided<<<512, 256, 0, stream>>>(Whh_f[2], WC2, 512, 1024, 512);
  for (int l = 0; l < 3; ++l)
    bias_sum<<<8, 256, 0, stream>>>(bih_f[l], bhh_f[l], BIAS + l * 2048, G4_);
  hipMemsetAsync(RINGS, 0, (size_t)3 * RING_N * 2, stream);
  hipMemsetAsync(FLAGS, 0, 3 * 512 * 4 * FSTR * 4, stream);

  lstm_persist<<<192, 512, 0, stream>>>(XBF, WC, BIAS, RINGS, HSF, FLAGS);
  fc_kernel<<<B_, 64, 0, stream>>>(HSF, Wfc, bfc, (float*)d_out);
}

// Round 10
// 3272.895 us; speedup vs baseline: 1.4719x; 1.4719x over previous
//
#include <hip/hip_runtime.h>

#define B_   256
#define T_   512
#define DIN_ 128
#define H_   512
#define G4_  2048

typedef __bf16 bf16_t;
typedef __bf16 bf16x8 __attribute__((ext_vector_type(8)));
typedef __bf16 bf16x4 __attribute__((ext_vector_type(4)));
typedef float  f32x4  __attribute__((ext_vector_type(4)));
typedef float  f32x16 __attribute__((ext_vector_type(16)));

// coherent-point read (sc0|sc1 = 1|16): bypass L1+L2, read the MALL
__device__ __forceinline__ void gload16cc(const void* g, void* l) {
  __builtin_amdgcn_global_load_lds(
      (const __attribute__((address_space(1))) unsigned int*)g,
      (__attribute__((address_space(3))) unsigned int*)l, 16, 0, 17);
}

// ---------------- prep ----------------
__global__ void cast_f32_bf16(const float* __restrict__ s, bf16_t* __restrict__ d, int n) {
  int i = (blockIdx.x * 256 + threadIdx.x) * 4;
  if (i >= n) return;
  float4 v = *(const float4*)(s + i);
  bf16x4 o;
  o[0] = (bf16_t)v.x; o[1] = (bf16_t)v.y; o[2] = (bf16_t)v.z; o[3] = (bf16_t)v.w;
  *(bf16x4*)(d + i) = o;
}

// src f32 [2048][Ks] -> dst bf16 rows stride Kd at col offset coff
__global__ void cast_strided(const float* __restrict__ s, bf16_t* __restrict__ d,
                             int Ks, int Kd, int coff) {
  int npr = Ks >> 3;
  int i = blockIdx.x * 256 + threadIdx.x;
  if (i >= 2048 * npr) return;
  int row = i / npr, j = i - row * npr;
  const float* sp = s + (size_t)row * Ks + j * 8;
  float4 v0 = *(const float4*)sp;
  float4 v1 = *(const float4*)(sp + 4);
  bf16x8 o;
  o[0] = (bf16_t)v0.x; o[1] = (bf16_t)v0.y; o[2] = (bf16_t)v0.z; o[3] = (bf16_t)v0.w;
  o[4] = (bf16_t)v1.x; o[5] = (bf16_t)v1.y; o[6] = (bf16_t)v1.z; o[7] = (bf16_t)v1.w;
  *(bf16x8*)(d + (size_t)row * Kd + coff + j * 8) = o;
}

__global__ void bias_sum(const float* __restrict__ a, const float* __restrict__ b,
                         float* __restrict__ o, int n) {
  int i = blockIdx.x * 256 + threadIdx.x;
  if (i < n) o[i] = a[i] + b[i];
}

// ---------------- persistent 3-layer LSTM ----------------
// Round-7 structure (known-good 3.35 ms). ONE change: X-MFMA split at XP1;
// {own/next poll, (c), stage-H issue} moved between the halves so the
// stage-H MALL RT is covered by X-part2. Everything else identical.
#define RING_N (8 * 256 * 512)
#define FSTR   16   // ints per flag (64B line)

template<bool L0>
__device__ __forceinline__ void step_loop(
    char* smem, const bf16_t* __restrict__ xbf, const bf16_t* __restrict__ wcl,
    const float* __restrict__ bias_l, bf16_t* ringPrev, bf16_t* ringOwn,
    float* __restrict__ hsf, int* flags, int layer, int bg, int ug)
{
  constexpr int KL   = L0 ? 640 : 1024;
  constexpr int ROWB = KL * 2;          // LDS row bytes
  constexpr int XT   = L0 ? 4 : 16;     // X-phase k-tiles(16) per wave
  constexpr int HT   = 16;              // H-phase k-tiles per wave
  constexpr int XP1  = L0 ? 2 : 8;      // X-MFMA tiles before stage-H issue
  constexpr int HOFF = L0 ? 256 : 1024; // byte offset of H region in a row
  const int tid  = threadIdx.x;
  const int lane = tid & 63;
  const int wv   = tid >> 6;
  const int g    = wv & 3;              // gate 0..3 (i,f,g,o)
  const int kh   = wv >> 2;             // K-half 0/1
  const int r32  = lane & 31;
  const int l5   = lane >> 5;
  const int u0   = ug * 32;
  const int t0x  = L0 ? (kh * 4) : (kh * 16);
  const int t0h  = L0 ? (8 + kh * 16) : (32 + kh * 16);

  // W fragments: lane holds W[g*512+u0+r32][tile*16 + l5*8 ..+8]
  bf16x8 wfrag[XT + HT];
  {
    const bf16_t* wrow = wcl + (size_t)(g * 512 + u0 + r32) * KL + l5 * 8;
    #pragma unroll
    for (int i = 0; i < XT; ++i) wfrag[i]      = *(const bf16x8*)(wrow + (t0x + i) * 16);
    #pragma unroll
    for (int i = 0; i < HT; ++i) wfrag[XT + i] = *(const bf16x8*)(wrow + (t0h + i) * 16);
  }
  const int um = tid >> 3;
  const int uq = tid & 7;
  float bsv[4][4];
  #pragma unroll
  for (int g2 = 0; g2 < 4; ++g2)
    #pragma unroll
    for (int q = 0; q < 4; ++q)
      bsv[g2][q] = bias_l[g2 * 512 + u0 + uq * 4 + q];

  float cst[4] = {0.f, 0.f, 0.f, 0.f};
  float* gp = (float*)smem;   // partials overlay: [2 kh][64 m][128 n] f32 = 64 KB

  int* fl_own  = flags + ((layer * 512) * 4 + bg) * FSTR;
  int* fl_prev = flags + (((layer - 1) * 512) * 4 + bg) * FSTR;
  int* fl_next = flags + (((layer + 1) * 512) * 4 + bg) * FSTR;

  for (int s = 0; s < 512; ++s) {
    const int slot  = s & 7;
    const int slot2 = (s - 1) & 7;
    // ================= Phase X: prev-layer input (no own-h dependency) =====
    if (!L0) {
      if (tid == 0)
        while (__hip_atomic_load(fl_prev + s * 4 * FSTR, __ATOMIC_RELAXED,
                                 __HIP_MEMORY_SCOPE_AGENT) < 16)
          __builtin_amdgcn_s_sleep(1);
      __syncthreads();                 // (a) flag visible; gp reads of s-1 done
      const bf16_t* prvS = ringPrev + (size_t)slot * (256 * 512) + (size_t)(bg * 64) * 512;
      #pragma unroll
      for (int i = 0; i < 8; ++i) {    // X region: chunks 0..63
        int r = i * 8 + wv;
        gload16cc(prvS + r * 512 + (lane ^ (r & 15)) * 8, smem + r * ROWB);
      }
    } else {
      #pragma unroll
      for (int i2 = 0; i2 < 2; ++i2) { // x-part: chunks 0..15 via regs
        int idx = i2 * 512 + tid;
        int r = idx >> 4, cx = idx & 15;
        int px = cx ^ (r & 15);
        bf16x8 v = *(const bf16x8*)(xbf + ((size_t)(bg * 64 + r) * T_ + s) * 128 + cx * 8);
        *(bf16x8*)(smem + r * ROWB + px * 16) = v;
      }
    }
    __syncthreads();                   // (b) X staged
    f32x16 acc0 = {}, acc1 = {};
    // ---- X-MFMA part 1
    #pragma unroll
    for (int i = 0; i < XP1; ++i) {
      const int px = ((t0x + i) * 2 + l5) ^ (r32 & 15);
      bf16x8 a0 = *(const bf16x8*)(smem + r32 * ROWB + px * 16);
      bf16x8 a1 = *(const bf16x8*)(smem + (32 + r32) * ROWB + px * 16);
      acc0 = __builtin_amdgcn_mfma_f32_32x32x16_bf16(a0, wfrag[i], acc0, 0, 0, 0);
      acc1 = __builtin_amdgcn_mfma_f32_32x32x16_bf16(a1, wfrag[i], acc1, 0, 0, 0);
    }
    // ---- own/next polls + stage-H issue (RT covered by X-part2)
    if (tid == 0) {
      if (s > 0)
        while (__hip_atomic_load(fl_own + (s - 1) * 4 * FSTR, __ATOMIC_RELAXED,
                                 __HIP_MEMORY_SCOPE_AGENT) < 16)
          __builtin_amdgcn_s_sleep(1);
      if (layer < 2 && s >= 8)         // ring back-pressure (depth 8)
        while (__hip_atomic_load(fl_next + (s - 8) * 4 * FSTR, __ATOMIC_RELAXED,
                                 __HIP_MEMORY_SCOPE_AGENT) < 16)
          __builtin_amdgcn_s_sleep(1);
    }
    __syncthreads();                   // (c) own flag seen by all
    {
      const bf16_t* ownS = ringOwn + (size_t)slot2 * (256 * 512) + (size_t)(bg * 64) * 512;
      #pragma unroll
      for (int i = 0; i < 8; ++i) {    // H region
        int r = i * 8 + wv;
        gload16cc(ownS + r * 512 + (lane ^ (r & 15)) * 8, smem + r * ROWB + HOFF);
      }
    }
    // ---- X-MFMA part 2 (covers stage-H round trip)
    #pragma unroll
    for (int i = XP1; i < XT; ++i) {
      const int px = ((t0x + i) * 2 + l5) ^ (r32 & 15);
      bf16x8 a0 = *(const bf16x8*)(smem + r32 * ROWB + px * 16);
      bf16x8 a1 = *(const bf16x8*)(smem + (32 + r32) * ROWB + px * 16);
      acc0 = __builtin_amdgcn_mfma_f32_32x32x16_bf16(a0, wfrag[i], acc0, 0, 0, 0);
      acc1 = __builtin_amdgcn_mfma_f32_32x32x16_bf16(a1, wfrag[i], acc1, 0, 0, 0);
    }
    __syncthreads();                   // (d) H staged + visible
    // ---- H-MFMA
    #pragma unroll
    for (int i = 0; i < HT; ++i) {
      const int px = ((t0h + i) * 2 + l5) ^ (r32 & 15);
      bf16x8 a0 = *(const bf16x8*)(smem + r32 * ROWB + px * 16);
      bf16x8 a1 = *(const bf16x8*)(smem + (32 + r32) * ROWB + px * 16);
      acc0 = __builtin_amdgcn_mfma_f32_32x32x16_bf16(a0, wfrag[XT + i], acc0, 0, 0, 0);
      acc1 = __builtin_amdgcn_mfma_f32_32x32x16_bf16(a1, wfrag[XT + i], acc1, 0, 0, 0);
    }
    __syncthreads();                   // (e) all A-reads done: gp overlay safe
    // ---- write partials: D col=lane&31 (n), row=(reg&3)+8*(reg>>2)+4*l5 (m)
    {
      const int base = kh * 8192 + g * 32 + r32;
      #pragma unroll
      for (int reg = 0; reg < 16; ++reg) {
        int mr = (reg & 3) + 8 * (reg >> 2) + 4 * l5;
        gp[base + mr * 128]        = acc0[reg];
        gp[base + (32 + mr) * 128] = acc1[reg];
      }
    }
    __syncthreads();                   // (f)
    // ---- lane-local c/h update (sum the 2 K-half partials)
    union { bf16x4 v; unsigned long long u; } pk;
    f32x4 hvf;
    {
      f32x4 gv[4];
      #pragma unroll
      for (int g2 = 0; g2 < 4; ++g2) {
        f32x4 p0 = *(const f32x4*)&gp[um * 128 + g2 * 32 + uq * 4];
        f32x4 p1 = *(const f32x4*)&gp[8192 + um * 128 + g2 * 32 + uq * 4];
        #pragma unroll
        for (int q = 0; q < 4; ++q) gv[g2][q] = p0[q] + p1[q];
      }
      #pragma unroll
      for (int q = 0; q < 4; ++q) {
        float i_ = gv[0][q] + bsv[0][q];
        float f_ = gv[1][q] + bsv[1][q];
        float g_ = gv[2][q] + bsv[2][q];
        float o_ = gv[3][q] + bsv[3][q];
        float si = 1.f / (1.f + __expf(-i_));
        float sf = 1.f / (1.f + __expf(-f_));
        float so = 1.f / (1.f + __expf(-o_));
        float tg = 2.f / (1.f + __expf(-2.f * g_)) - 1.f;
        float cv = sf * cst[q] + si * tg;
        cst[q] = cv;
        float th = 2.f / (1.f + __expf(-2.f * cv)) - 1.f;
        hvf[q] = so * th;
        pk.v[q] = (bf16_t)hvf[q];
      }
    }
    // ---- publish h at the MALL (atomic RMW executes/allocates at MALL)
    {
      int b = bg * 64 + um;
      bf16_t* dst = ringOwn + (size_t)slot * (256 * 512) + (size_t)b * 512 + u0 + uq * 4;
      (void)__hip_atomic_exchange((unsigned long long*)dst, pk.u,
                                  __ATOMIC_RELAXED, __HIP_MEMORY_SCOPE_AGENT);
      if (layer == 2 && s == 511)
        *(f32x4*)(hsf + (size_t)b * 512 + u0 + uq * 4) = hvf;
    }
    __syncthreads();                   // (g) vmcnt(0): h-swaps acked at MALL
    if (tid == 0)
      atomicAdd(fl_own + s * 4 * FSTR, 1);   // fire-and-forget
  }
}

__global__ __launch_bounds__(512, 2)
void lstm_persist(const bf16_t* __restrict__ xbf, const bf16_t* __restrict__ wc,
                  const float* __restrict__ bias, bf16_t* __restrict__ rings,
                  float* __restrict__ hsf, int* __restrict__ flags)
{
  __shared__ __align__(16) char smem[131072];
  const int bid   = blockIdx.x;
  const int layer = bid >> 6;
  const int bg    = (bid >> 4) & 3;
  const int ug    = bid & 15;
  bf16_t* ringOwn  = rings + (size_t)layer * RING_N;
  bf16_t* ringPrev = rings + (size_t)(layer - 1) * RING_N;  // unused for layer0
  if (layer == 0) {
    step_loop<true>(smem, xbf, wc, bias, ringPrev, ringOwn, hsf, flags, 0, bg, ug);
  } else {
    const bf16_t* wcl = wc + 2048 * 640 + (size_t)(layer - 1) * 2048 * 1024;
    step_loop<false>(smem, xbf, wcl, bias + layer * 2048, ringPrev, ringOwn, hsf,
                     flags, layer, bg, ug);
  }
}

// ---------------- final FC ----------------
__global__ void fc_kernel(const float* __restrict__ h, const float* __restrict__ Wfc,
                          const float* __restrict__ bfc, float* __restrict__ out) {
  int b = blockIdx.x;
  int l = threadIdx.x;
  const float* hp = h + (size_t)b * H_;
  float acc = 0.f;
  #pragma unroll
  for (int i = 0; i < 8; ++i) acc += hp[l + i * 64] * Wfc[l + i * 64];
  #pragma unroll
  for (int off = 32; off; off >>= 1) acc += __shfl_down(acc, off, 64);
  if (l == 0) out[b] = acc + bfc[0];
}

// ---------------- host ----------------
extern "C" void kernel_launch(void* const* d_in, const int* in_sizes, int n_in,
                              void* d_out, int out_size, void* d_ws, size_t ws_size,
                              hipStream_t stream) {
  const float* x        = (const float*)d_in[0];
  const float* Wih_f[3] = {(const float*)d_in[1], (const float*)d_in[5], (const float*)d_in[9]};
  const float* Whh_f[3] = {(const float*)d_in[2], (const float*)d_in[6], (const float*)d_in[10]};
  const float* bih_f[3] = {(const float*)d_in[3], (const float*)d_in[7], (const float*)d_in[11]};
  const float* bhh_f[3] = {(const float*)d_in[4], (const float*)d_in[8], (const float*)d_in[12]};
  const float* Wfc = (const float*)d_in[13];
  const float* bfc = (const float*)d_in[14];

  char* ws = (char*)d_ws;
  size_t off = 0;
  auto take = [&](size_t bytes) { char* p = ws + off; off = (off + bytes + 255) & ~255ULL; return p; };
  bf16_t* XBF   = (bf16_t*)take((size_t)B_ * T_ * DIN_ * 2);        // 33.6 MB
  bf16_t* WC    = (bf16_t*)take((size_t)(2048*640 + 2*2048*1024) * 2); // 11.0 MB
  float*  BIAS  = (float*) take(3 * 2048 * 4);
  bf16_t* RINGS = (bf16_t*)take((size_t)3 * RING_N * 2);            // 6.3 MB
  float*  HSF   = (float*) take((size_t)B_ * H_ * 4);
  int*    FLAGS = (int*)   take(3 * 512 * 4 * FSTR * 4);            // 64B/flag

  bf16_t* WC1 = WC + 2048 * 640;
  bf16_t* WC2 = WC1 + 2048 * 1024;

  // weights / x prep
  cast_f32_bf16<<<16384, 256, 0, stream>>>(x, XBF, B_ * T_ * DIN_);
  cast_strided<<<128, 256, 0, stream>>>(Wih_f[0], WC,  128, 640, 0);
  cast_strided<<<512, 256, 0, stream>>>(Whh_f[0], WC,  512, 640, 128);
  cast_strided<<<512, 256, 0, stream>>>(Wih_f[1], WC1, 512, 1024, 0);
  cast_strided<<<512, 256, 0, stream>>>(Whh_f[1], WC1, 512, 1024, 512);
  cast_strided<<<512, 256, 0, stream>>>(Wih_f[2], WC2, 512, 1024, 0);
  cast_strided<<<512, 256, 0, stream>>>(Whh_f[2], WC2, 512, 1024, 512);
  for (int l = 0; l < 3; ++l)
    bias_sum<<<8, 256, 0, stream>>>(bih_f[l], bhh_f[l], BIAS + l * 2048, G4_);
  hipMemsetAsync(RINGS, 0, (size_t)3 * RING_N * 2, stream);
  hipMemsetAsync(FLAGS, 0, 3 * 512 * 4 * FSTR * 4, stream);

  lstm_persist<<<192, 512, 0, stream>>>(XBF, WC, BIAS, RINGS, HSF, FLAGS);
  fc_kernel<<<B_, 64, 0, stream>>>(HSF, Wfc, bfc, (float*)d_out);
}